// Round 10
// baseline (382.666 us; speedup 1.0000x reference)
//
#include <hip/hip_runtime.h>
#include <hip/hip_bf16.h>
#include <math.h>
#include <type_traits>

#define BATCH 2
#define SEQ   2048
#define DMODEL 768
#define DIN   384
#define DINNER 768
#define DSTATE 16
#define DTRANK 24
#define ROWS  (BATCH*SEQ)   // 4096
#define NCH   64            // time chunks for the scan
#define CLEN  (SEQ/NCH)     // 32 steps per chunk

using short8  = __attribute__((ext_vector_type(8))) short;
using floatx4 = __attribute__((ext_vector_type(4))) float;

__device__ __forceinline__ ushort f2bf(float f) {
    union { float f; uint u; } v; v.f = f;
    uint r = (v.u + 0x7fffu + ((v.u >> 16) & 1u)) >> 16;
    return (ushort)r;
}
__device__ __forceinline__ float bf2f(ushort h) {
    union { uint u; float f; } v; v.u = ((uint)h) << 16;
    return v.f;
}
__device__ __forceinline__ void async16(const ushort* g, ushort* l) {
    __builtin_amdgcn_global_load_lds(
        (const __attribute__((address_space(1))) void*)g,
        (__attribute__((address_space(3))) void*)l,
        16, 0, 0);
}
// softplus via fast HW transcendentals (v_exp_f32 + v_log_f32)
__device__ __forceinline__ float softplus_fast(float v) {
    if (v > 20.f) return v;
    float e = __expf(-fabsf(v));
    return fmaxf(v, 0.f) + __logf(1.f + e);
}

// ---------------------------------------------------------------------------
// MFMA GEMM building blocks (m97 staging, BK=64, XOR-swizzled LDS).
// Physical granule p of row r holds logical granule p^(r&7). [R7: conflicts 0]
// ---------------------------------------------------------------------------
template<int TM, int TN> struct GemmShT { ushort lA[TM * 64]; ushort lB[TN * 64]; };

template<int TM, int TN>
__device__ __forceinline__ void gemm_accum(
    const ushort* __restrict__ A, int lda,
    const ushort* __restrict__ Bt, int ldb,
    int K, int m0, int n0, GemmShT<TM, TN>& sh,
    floatx4 (&acc)[TM / 32][TN / 32])
{
    constexpr int WM = TM / 2, WN = TN / 2;
    constexpr int MT = WM / 16, NT = WN / 16;
    constexpr int AI = TM / 32, BI = TN / 32;
    const int tid = threadIdx.x;
    const int wave = tid >> 6, lane = tid & 63;
    const int wm = wave >> 1, wn = wave & 1;
    const int quad = lane >> 4, l16 = lane & 15;
    const int lrow = lane >> 3;                      // 8 rows per 1KB wave-store
    const int lcol = ((lane & 7) ^ (lane >> 3)) * 8; // XOR-swizzled source granule

    for (int k0 = 0; k0 < K; k0 += 64) {
#pragma unroll
        for (int i = 0; i < AI; i++) {
            int rb = (wave * AI + i) * 8;
            async16(A + (size_t)(m0 + rb + lrow) * lda + k0 + lcol, &sh.lA[rb * 64]);
        }
#pragma unroll
        for (int i = 0; i < BI; i++) {
            int rb = (wave * BI + i) * 8;
            async16(Bt + (size_t)(n0 + rb + lrow) * ldb + k0 + lcol, &sh.lB[rb * 64]);
        }
        __syncthreads();
#pragma unroll
        for (int ks = 0; ks < 2; ks++) {
            short8 af[MT], bf[NT];
#pragma unroll
            for (int i = 0; i < MT; i++) {
                int row = wm * WM + i * 16 + l16;
                af[i] = *(const short8*)&sh.lA[row * 64 + ((ks * 4 + quad) ^ (row & 7)) * 8];
            }
#pragma unroll
            for (int j = 0; j < NT; j++) {
                int row = wn * WN + j * 16 + l16;
                bf[j] = *(const short8*)&sh.lB[row * 64 + ((ks * 4 + quad) ^ (row & 7)) * 8];
            }
#pragma unroll
            for (int i = 0; i < MT; i++)
#pragma unroll
                for (int j = 0; j < NT; j++)
                    acc[i][j] = __builtin_amdgcn_mfma_f32_16x16x32_bf16(af[i], bf[j], acc[i][j], 0, 0, 0);
        }
        __syncthreads();
    }
}

template<int TM, int TN, bool OUT_BF>
__device__ __forceinline__ void gemm_epilogue(
    const float* __restrict__ bias, void* __restrict__ C, int ldc, int N,
    int m0, int n0, floatx4 (&acc)[TM / 32][TN / 32])
{
    constexpr int WM = TM / 2, WN = TN / 2;
    constexpr int MT = WM / 16, NT = WN / 16;
    const int tid = threadIdx.x;
    const int wave = tid >> 6, lane = tid & 63;
    const int wm = wave >> 1, wn = wave & 1;
    const int quad = lane >> 4, l16 = lane & 15;
#pragma unroll
    for (int i = 0; i < MT; i++) {
#pragma unroll
        for (int j = 0; j < NT; j++) {
            int row = m0 + wm * WM + i * 16 + quad * 4;
            int col = n0 + wn * WN + j * 16 + l16;
            if (col < N) {
                float bv = bias ? bias[col] : 0.f;
#pragma unroll
                for (int r = 0; r < 4; r++) {
                    float v = acc[i][j][r] + bv;
                    if (OUT_BF) ((ushort*)C)[(size_t)(row + r) * ldc + col] = f2bf(v);
                    else        ((float*)C)[(size_t)(row + r) * ldc + col] = v;
                }
            }
        }
    }
}

// Generic single-pair GEMM kernel; grid.z selects f/b operand sets.
template<int TM, int TN, bool OUT_BF>
__global__ __launch_bounds__(256) void mfma_gemm_k(
    const ushort* __restrict__ A0, const ushort* __restrict__ A1, int lda,
    const ushort* __restrict__ B0, const ushort* __restrict__ B1, int ldb,
    const float* __restrict__ bias0, const float* __restrict__ bias1,
    void* __restrict__ C0, void* __restrict__ C1, int ldc, int N, int K)
{
    __shared__ GemmShT<TM, TN> sh;
    const ushort* A  = blockIdx.z ? A1 : A0;
    const ushort* Bt = blockIdx.z ? B1 : B0;
    const float* bias = blockIdx.z ? bias1 : bias0;
    void* C = blockIdx.z ? C1 : C0;
    floatx4 acc[TM / 32][TN / 32];
#pragma unroll
    for (int i = 0; i < TM / 32; i++)
#pragma unroll
        for (int j = 0; j < TN / 32; j++)
            acc[i][j] = (floatx4){0.f, 0.f, 0.f, 0.f};
    int m0 = blockIdx.y * TM, n0 = blockIdx.x * TN;
    gemm_accum<TM, TN>(A, lda, Bt, ldb, K, m0, n0, sh, acc);
    gemm_epilogue<TM, TN, OUT_BF>(bias, C, ldc, N, m0, n0, acc);
}

// ---------------------------------------------------------------------------
// Fused conv+silu -> xd64 -> dt kernel (replaces 3 dispatches).
// Phase A: A-tile staged by computing conv(xz)+silu in registers (VALU
//   staging, 64x64 tile, 3-row halo), K=768 MFMA vs Wxp -> xd64 tile;
//   written to global (bf16, scan B/C source) and swizzled LDS.
// Phase B: 12 tiles of dt = softplus(xd[.,0..23] @ dtw + b) via K=64 MFMA
//   against zero-padded dtwT (rows 24..63 zero annihilate B/C cols).
// ---------------------------------------------------------------------------
__global__ __launch_bounds__(256) void xddt_kernel(
    const ushort* __restrict__ xzf, const ushort* __restrict__ xzb,
    const float* __restrict__ cwf, const float* __restrict__ cbf,
    const float* __restrict__ cwb, const float* __restrict__ cbb,
    const ushort* __restrict__ WxpF, const ushort* __restrict__ WxpB,
    const ushort* __restrict__ dtwTf, const ushort* __restrict__ dtwTb,
    const float* __restrict__ dtbf, const float* __restrict__ dtbb,
    ushort* __restrict__ xdf, ushort* __restrict__ xdb,
    ushort* __restrict__ dtf, ushort* __restrict__ dtb)
{
    __shared__ ushort lA[64 * 64];
    __shared__ ushort lB[64 * 64];
    const int dir = blockIdx.z;
    const ushort* xz = dir ? xzb : xzf;
    const float* cw = dir ? cwb : cwf;
    const float* cb = dir ? cbb : cbf;
    const ushort* Wxp  = dir ? WxpB : WxpF;
    const ushort* dtwT = dir ? dtwTb : dtwTf;
    const float* dtbias = dir ? dtbb : dtbf;
    ushort* xd = dir ? xdb : xdf;
    ushort* dt = dir ? dtb : dtf;
    const int m0 = blockIdx.y * 64;
    const int tid = threadIdx.x;
    const int wave = tid >> 6, lane = tid & 63;
    const int wm = wave >> 1, wn = wave & 1;
    const int quad = lane >> 4, l16 = lane & 15;
    const int lrow = lane >> 3, lcol = ((lane & 7) ^ (lane >> 3)) * 8;

    floatx4 acc[2][2];
#pragma unroll
    for (int i = 0; i < 2; i++)
#pragma unroll
        for (int j = 0; j < 2; j++)
            acc[i][j] = (floatx4){0.f, 0.f, 0.f, 0.f};

    // ---- phase A: K-loop with conv-staged A ----
    for (int k0 = 0; k0 < 768; k0 += 64) {
#pragma unroll
        for (int c = 0; c < 2; c++) {
            int flat = tid + c * 256;
            int row = flat >> 3, colg = flat & 7;
            int r = m0 + row, b = r >> 11, t = r & (SEQ - 1);
            int d0 = k0 + colg * 8;
            float a8[8];
#pragma unroll
            for (int cc = 0; cc < 8; cc++) a8[cc] = cb[d0 + cc];
#pragma unroll
            for (int kk = 0; kk < 4; kk++) {
                int ts = dir ? (t + 3 - kk) : (t - 3 + kk);
                if (ts >= 0 && ts < SEQ) {
                    short8 v = *(const short8*)&xz[((size_t)(b * SEQ + ts)) * 1536 + d0];
#pragma unroll
                    for (int cc = 0; cc < 8; cc++)
                        a8[cc] = fmaf(cw[(d0 + cc) * 4 + kk], bf2f((ushort)v[cc]), a8[cc]);
                }
            }
            short8 o;
#pragma unroll
            for (int cc = 0; cc < 8; cc++) {
                float sig = 1.f / (1.f + __expf(-a8[cc]));
                o[cc] = (short)f2bf(a8[cc] * sig);
            }
            *(short8*)&lA[row * 64 + ((colg ^ (row & 7)) * 8)] = o;
        }
#pragma unroll
        for (int i = 0; i < 2; i++) {
            int rb = (wave * 2 + i) * 8;
            async16(Wxp + (size_t)(rb + lrow) * 768 + k0 + lcol, &lB[rb * 64]);
        }
        __syncthreads();
#pragma unroll
        for (int ks = 0; ks < 2; ks++) {
            short8 af[2], bfr[2];
#pragma unroll
            for (int i = 0; i < 2; i++) {
                int row = wm * 32 + i * 16 + l16;
                af[i] = *(const short8*)&lA[row * 64 + ((ks * 4 + quad) ^ (row & 7)) * 8];
            }
#pragma unroll
            for (int j = 0; j < 2; j++) {
                int row = wn * 32 + j * 16 + l16;
                bfr[j] = *(const short8*)&lB[row * 64 + ((ks * 4 + quad) ^ (row & 7)) * 8];
            }
#pragma unroll
            for (int i = 0; i < 2; i++)
#pragma unroll
                for (int j = 0; j < 2; j++)
                    acc[i][j] = __builtin_amdgcn_mfma_f32_16x16x32_bf16(af[i], bfr[j], acc[i][j], 0, 0, 0);
        }
        __syncthreads();
    }

    // ---- xd64 epilogue: global (bf16) + swizzled LDS for phase B ----
#pragma unroll
    for (int i = 0; i < 2; i++) {
#pragma unroll
        for (int j = 0; j < 2; j++) {
            int lr0 = wm * 32 + i * 16 + quad * 4;
            int col = wn * 32 + j * 16 + l16;
#pragma unroll
            for (int r = 0; r < 4; r++) {
                int lr = lr0 + r;
                ushort hv = f2bf(acc[i][j][r]);
                xd[(size_t)(m0 + lr) * 64 + col] = hv;
                lA[lr * 64 + ((col >> 3) ^ (lr & 7)) * 8 + (col & 7)] = hv;
            }
        }
    }
    __syncthreads();

    // ---- phase B: dt tiles (K=64) ----
    for (int nt = 0; nt < 12; nt++) {
#pragma unroll
        for (int i = 0; i < 2; i++) {
            int rb = (wave * 2 + i) * 8;
            async16(dtwT + (size_t)(nt * 64 + rb + lrow) * 64 + lcol, &lB[rb * 64]);
        }
        __syncthreads();
        floatx4 a2[2][2];
#pragma unroll
        for (int i = 0; i < 2; i++)
#pragma unroll
            for (int j = 0; j < 2; j++)
                a2[i][j] = (floatx4){0.f, 0.f, 0.f, 0.f};
#pragma unroll
        for (int ks = 0; ks < 2; ks++) {
            short8 af[2], bfr[2];
#pragma unroll
            for (int i = 0; i < 2; i++) {
                int row = wm * 32 + i * 16 + l16;
                af[i] = *(const short8*)&lA[row * 64 + ((ks * 4 + quad) ^ (row & 7)) * 8];
            }
#pragma unroll
            for (int j = 0; j < 2; j++) {
                int row = wn * 32 + j * 16 + l16;
                bfr[j] = *(const short8*)&lB[row * 64 + ((ks * 4 + quad) ^ (row & 7)) * 8];
            }
#pragma unroll
            for (int i = 0; i < 2; i++)
#pragma unroll
                for (int j = 0; j < 2; j++)
                    a2[i][j] = __builtin_amdgcn_mfma_f32_16x16x32_bf16(af[i], bfr[j], a2[i][j], 0, 0, 0);
        }
#pragma unroll
        for (int i = 0; i < 2; i++) {
#pragma unroll
            for (int j = 0; j < 2; j++) {
                int row = m0 + wm * 32 + i * 16 + quad * 4;
                int col = nt * 64 + wn * 32 + j * 16 + l16;
                float bv = dtbias[col];
#pragma unroll
                for (int r = 0; r < 4; r++)
                    dt[(size_t)(row + r) * 768 + col] = f2bf(softplus_fast(a2[i][j][r] + bv));
            }
        }
        __syncthreads();
    }
}

// Dual-A GEMM: C = A0@B0^T + A1@B1^T + bias (fused out+op projection).
template<int TM, int TN>
__global__ __launch_bounds__(256) void outop_kernel(
    const ushort* __restrict__ A0, const ushort* __restrict__ B0,
    const ushort* __restrict__ A1, const ushort* __restrict__ B1,
    const float* __restrict__ bias, float* __restrict__ C,
    int lda, int ldb, int ldc, int N, int K)
{
    __shared__ GemmShT<TM, TN> sh;
    floatx4 acc[TM / 32][TN / 32];
#pragma unroll
    for (int i = 0; i < TM / 32; i++)
#pragma unroll
        for (int j = 0; j < TN / 32; j++)
            acc[i][j] = (floatx4){0.f, 0.f, 0.f, 0.f};
    int m0 = blockIdx.y * TM, n0 = blockIdx.x * TN;
    gemm_accum<TM, TN>(A0, lda, B0, ldb, K, m0, n0, sh, acc);
    gemm_accum<TM, TN>(A1, lda, B1, ldb, K, m0, n0, sh, acc);
    gemm_epilogue<TM, TN, false>(bias, (void*)C, ldc, N, m0, n0, acc);
}

// ---------------------------------------------------------------------------
// LayerNorm row helper (+ standalone kernel for the final LN).
// ---------------------------------------------------------------------------
struct LnSh { float ss[4]; float ssq[4]; float m; float rs; };

template<bool OUT_BF>
__device__ __forceinline__ void ln_row(
    int row, const float* __restrict__ x, const float* __restrict__ res,
    const float* __restrict__ w, const float* __restrict__ b,
    void* __restrict__ out, LnSh& sh)
{
    int tid = threadIdx.x;
    const float* xr = x + (size_t)row * DMODEL;
    const float* rr = res ? res + (size_t)row * DMODEL : nullptr;
    float v[3];
    float s = 0.f, sq = 0.f;
#pragma unroll
    for (int j = 0; j < 3; j++) {
        int i = tid + j * 256;
        float val = xr[i];
        if (rr) val += rr[i];
        v[j] = val; s += val; sq += val * val;
    }
#pragma unroll
    for (int off = 32; off; off >>= 1) {
        s  += __shfl_down(s,  off);
        sq += __shfl_down(sq, off);
    }
    int wid = tid >> 6;
    if ((tid & 63) == 0) { sh.ss[wid] = s; sh.ssq[wid] = sq; }
    __syncthreads();
    if (tid == 0) {
        float S  = sh.ss[0] + sh.ss[1] + sh.ss[2] + sh.ss[3];
        float SQ = sh.ssq[0] + sh.ssq[1] + sh.ssq[2] + sh.ssq[3];
        float m  = S * (1.0f / DMODEL);
        float var = SQ * (1.0f / DMODEL) - m * m;
        sh.m = m;
        sh.rs = rsqrtf(var + 1e-5f);
    }
    __syncthreads();
    float m = sh.m, rs = sh.rs;
#pragma unroll
    for (int j = 0; j < 3; j++) {
        int i = tid + j * 256;
        float r = (v[j] - m) * rs * w[i] + b[i];
        if (OUT_BF) ((ushort*)out)[(size_t)row * DMODEL + i] = f2bf(r);
        else        ((float*)out)[(size_t)row * DMODEL + i] = r;
    }
}

__global__ __launch_bounds__(256) void ln2_kernel(
    const float* __restrict__ x, const float* __restrict__ res,
    const float* __restrict__ w, const float* __restrict__ b,
    float* __restrict__ out)
{
    __shared__ LnSh sh;
    ln_row<false>(blockIdx.x, x, res, w, b, (void*)out, sh);
}

// ---------------------------------------------------------------------------
// Prep: weight transpose/cast with zero-padding + input LN.
// ---------------------------------------------------------------------------
struct TD { const float* src; ushort* dst; int K, N, Kp, Np, ldd, tile0, tkp, mode; };
struct PrepArgs {
    TD d[12];
    int ntc;
    const float *x, *in_nw, *in_nb;
    ushort* xn;
};

__global__ __launch_bounds__(256) void prep_kernel(PrepArgs p)
{
    __shared__ union { float tile[32][33]; LnSh l; } sh;
    int bi = blockIdx.x;
    if (bi < p.ntc) {
        int i = 0;
        while (i < 11 && bi >= p.d[i + 1].tile0) i++;
        TD t = p.d[i];
        int local = bi - t.tile0;
        int tki = local % t.tkp, tn = local / t.tkp;
        int k0 = tki * 32, n0 = tn * 32;
        if (t.mode == 0) {
            int tx = threadIdx.x & 31, ty = threadIdx.x >> 5;
#pragma unroll
            for (int r = ty; r < 32; r += 8) {
                int k = k0 + r, n = n0 + tx;
                sh.tile[r][tx] = (k < t.K && n < t.N) ? t.src[(size_t)k * t.N + n] : 0.f;
            }
            __syncthreads();
#pragma unroll
            for (int r = ty; r < 32; r += 8) {
                int n = n0 + r, k = k0 + tx;
                t.dst[(size_t)n * t.ldd + k] = f2bf(sh.tile[tx][r]);
            }
        } else {
#pragma unroll
            for (int e = threadIdx.x; e < 1024; e += 256) {
                int r = e >> 5, c = e & 31;
                int k = k0 + r, n = n0 + c;
                float v = (k < t.K && n < t.N) ? t.src[(size_t)k * t.N + n] : 0.f;
                t.dst[(size_t)k * t.ldd + n] = f2bf(v);
            }
        }
    } else {
        ln_row<true>(bi - p.ntc, p.x, (const float*)nullptr, p.in_nw, p.in_nb,
                     (void*)p.xn, sh.l);
    }
}

// ---------------------------------------------------------------------------
// Weight-fusion dispatch: GEMV blocks first (ids 0..14), unrolled x16.
// ---------------------------------------------------------------------------
struct WfArgs {
    const ushort *fin, *bin, *opT, *ipc, *fow, *bow;
    ushort *WzF, *WzB, *WoF, *WoB;
    const float *ip_b, *f_in_b, *b_in_b, *f_out_b, *b_out_b, *op_b;
    const float *f_in_w32, *b_in_w32, *op_w32;
    float *bzf, *bzb, *bo;
};

__global__ __launch_bounds__(256) void wfuse_kernel(WfArgs p)
{
    __shared__ GemmShT<128, 64> sh;
    int t = blockIdx.x;
    if (t < 6) {                   // bz_f
        int n = t * 256 + threadIdx.x;
        float acc = p.f_in_b[n];
#pragma unroll 16
        for (int j = 0; j < 384; j++)
            acc = fmaf(p.ip_b[j], p.f_in_w32[(size_t)j * 1536 + n], acc);
        p.bzf[n] = acc;
    } else if (t < 12) {           // bz_b
        int n = (t - 6) * 256 + threadIdx.x;
        float acc = p.b_in_b[n];
#pragma unroll 16
        for (int j = 0; j < 384; j++)
            acc = fmaf(p.ip_b[384 + j], p.b_in_w32[(size_t)j * 1536 + n], acc);
        p.bzb[n] = acc;
    } else if (t < 15) {           // bo
        int n = (t - 12) * 256 + threadIdx.x;
        float acc = p.op_b[n];
#pragma unroll 16
        for (int j = 0; j < 384; j++)
            acc = fmaf(p.f_out_b[j], p.op_w32[(size_t)j * 768 + n], acc);
#pragma unroll 16
        for (int j = 0; j < 384; j++)
            acc = fmaf(p.b_out_b[j], p.op_w32[(size_t)(384 + j) * 768 + n], acc);
        p.bo[n] = acc;
    } else {
        int g = t - 15;
        const ushort *A, *Bt; ushort* C; int lda, ldb, m0, n0;
        if (g < 144)      { A = p.fin;       lda = 384; Bt = p.ipc;       ldb = 768; C = p.WzF; int u = g;       m0 = (u / 12) * 128; n0 = (u % 12) * 64; }
        else if (g < 288) { A = p.bin;       lda = 384; Bt = p.ipc + 384; ldb = 768; C = p.WzB; int u = g - 144; m0 = (u / 12) * 128; n0 = (u % 12) * 64; }
        else if (g < 360) { A = p.opT;       lda = 768; Bt = p.fow;       ldb = 384; C = p.WoF; int u = g - 288; m0 = (u / 12) * 128; n0 = (u % 12) * 64; }
        else              { A = p.opT + 384; lda = 768; Bt = p.bow;       ldb = 384; C = p.WoB; int u = g - 360; m0 = (u / 12) * 128; n0 = (u % 12) * 64; }
        floatx4 acc[4][2];
#pragma unroll
        for (int i = 0; i < 4; i++)
#pragma unroll
            for (int j = 0; j < 2; j++)
                acc[i][j] = (floatx4){0.f, 0.f, 0.f, 0.f};
        gemm_accum<128, 64>(A, lda, Bt, ldb, 384, m0, n0, sh, acc);
        gemm_epilogue<128, 64, true>((const float*)nullptr, (void*)C, 768, 768, m0, n0, acc);
    }
}

// ---------------------------------------------------------------------------
// Chunked selective scan (NCH=64, CLEN=32). conv+silu computed INLINE via a
// 4-deep rolling register window over xz (x-half); xc tensor eliminated.
// dt bf16; B/C from bf16 xd64 (wave-uniform).
// ---------------------------------------------------------------------------
template<bool FULL>
__global__ __launch_bounds__(256) void scan_chunk_kernel(
    const ushort* __restrict__ dtf, const ushort* __restrict__ xdf,
    const ushort* __restrict__ xzf,
    const float* __restrict__ cwf, const float* __restrict__ cbf,
    const float* __restrict__ Alf, const float* __restrict__ Dff,
    const ushort* __restrict__ dtb, const ushort* __restrict__ xdb,
    const ushort* __restrict__ xzb,
    const float* __restrict__ cwb, const float* __restrict__ cbb,
    const float* __restrict__ Alb, const float* __restrict__ Dbb,
    float* __restrict__ Hloc, float* __restrict__ Wp,
    const float* __restrict__ Hin,
    ushort* __restrict__ yf, ushort* __restrict__ yb)
{
    const int d     = blockIdx.x * 256 + threadIdx.x;
    const int chunk = blockIdx.y;
    const int bz    = blockIdx.z;
    const int dir   = bz >> 1;
    const int bat   = bz & 1;

    const ushort* dt = dir ? dtb : dtf;
    const ushort* xd = dir ? xdb : xdf;
    const ushort* xz = dir ? xzb : xzf;
    const float*  cw = dir ? cwb : cwf;
    const float*  cb = dir ? cbb : cbf;
    const float*  Al = dir ? Alb : Alf;
    const float*  Dp = dir ? Dbb : Dff;
    ushort* yo = dir ? yb : yf;

    float a[16];
    {
        const float4* Ap = (const float4*)(Al + (size_t)d * 16);
#pragma unroll
        for (int q = 0; q < 4; q++) {
            float4 v = Ap[q];
            a[q*4+0] = -__expf(v.x); a[q*4+1] = -__expf(v.y);
            a[q*4+2] = -__expf(v.z); a[q*4+3] = -__expf(v.w);
        }
    }
    const float a0 = a[0];
    bool fast = true;
#pragma unroll
    for (int n = 0; n < 16; n++) {
        float ideal = a0 * (float)(n + 1);
        fast = fast && (fabsf(a[n] - ideal) <= 1e-4f * fabsf(ideal) + 1e-7f);
    }

    float h[16];
    if (FULL) {
        size_t base = ((size_t)(bz * NCH + chunk) * DINNER + d) * 16;
#pragma unroll
        for (int q = 0; q < 4; q++) {
            float4 v = *(const float4*)(Hin + base + q * 4);
            h[q*4+0] = v.x; h[q*4+1] = v.y; h[q*4+2] = v.z; h[q*4+3] = v.w;
        }
    } else {
#pragma unroll
        for (int n = 0; n < 16; n++) h[n] = 0.f;
    }

    const float Dd = FULL ? Dp[d] : 0.f;
    const float4 w4 = *(const float4*)&cw[d * 4];
    const float cbd = cb[d];
    float S = 0.f;

    // conv rolling window preload
    float win0, win1, win2;
    {
        int t0 = dir ? (SEQ - 1 - chunk * CLEN) : chunk * CLEN;
        auto ldu = [&](int ts) -> float {
            return (ts >= 0 && ts < SEQ)
                ? bf2f(xz[((size_t)(bat * SEQ + ts)) * 1536 + d]) : 0.f;
        };
        if (!dir) { win0 = ldu(t0 - 3); win1 = ldu(t0 - 2); win2 = ldu(t0 - 1); }
        else      { win0 = ldu(t0 + 3); win1 = ldu(t0 + 2); win2 = ldu(t0 + 1); }
    }

    auto run = [&](auto FASTC) {
        constexpr bool FAST = decltype(FASTC)::value;
#pragma unroll 2
        for (int i = 0; i < CLEN; i++) {
            int tl = chunk * CLEN + i;
            int t  = dir ? (SEQ - 1 - tl) : tl;
            size_t r = (size_t)(bat * SEQ + t);
            float dtv = bf2f(dt[r * DINNER + d]);
            // inline conv + silu
            float cur = bf2f(xz[r * 1536 + d]);
            float cv = cbd;
            cv = fmaf(w4.x, win0, cv);
            cv = fmaf(w4.y, win1, cv);
            cv = fmaf(w4.z, win2, cv);
            cv = fmaf(w4.w, cur, cv);
            win0 = win1; win1 = win2; win2 = cur;
            float csig = 1.f / (1.f + __expf(-cv));
            float xv = cv * csig;

            const ushort* bp = xd + r * 64 + DTRANK;   // wave-uniform
            short8 b0 = *(const short8*)(bp);
            short8 b1 = *(const short8*)(bp + 8);
            float Bv[16];
#pragma unroll
            for (int n = 0; n < 8; n++) {
                Bv[n]     = bf2f((ushort)b0[n]);
                Bv[8 + n] = bf2f((ushort)b1[n]);
            }
            float w[16];
            if (FAST) {
                float e1 = __expf(dtv * a0);
                float e2 = e1*e1, e4 = e2*e2, e8 = e4*e4;
                w[0]=e1;      w[1]=e2;      w[2]=e2*e1;   w[3]=e4;
                w[4]=e4*e1;   w[5]=e4*e2;   w[6]=e4*w[2]; w[7]=e8;
                w[8]=e8*e1;   w[9]=e8*e2;   w[10]=e8*w[2];w[11]=e8*e4;
                w[12]=e8*w[4];w[13]=e8*w[5];w[14]=e8*w[6];w[15]=e8*e8;
            } else {
#pragma unroll
                for (int n = 0; n < 16; n++) w[n] = __expf(dtv * a[n]);
            }
            float bx = dtv * xv;
#pragma unroll
            for (int n = 0; n < 16; n++)
                h[n] = fmaf(w[n], h[n], bx * Bv[n]);
            S += dtv;
            if (FULL) {
                short8 c0 = *(const short8*)(bp + 16);
                short8 c1 = *(const short8*)(bp + 24);
                float Cv[16];
#pragma unroll
                for (int n = 0; n < 8; n++) {
                    Cv[n]     = bf2f((ushort)c0[n]);
                    Cv[8 + n] = bf2f((ushort)c1[n]);
                }
                float y = 0.f;
#pragma unroll
                for (int n = 0; n < 16; n++) y = fmaf(h[n], Cv[n], y);
                float zv = bf2f(xz[r * 1536 + DINNER + d]);
                float sig = 1.f / (1.f + __expf(-zv));
                yo[r * DINNER + d] = f2bf((y + xv * Dd) * (zv * sig));
            }
        }
    };
    if (fast) run(std::true_type{}); else run(std::false_type{});

    if (!FULL) {
        float W[16];
        if (fast) {
            float E1 = __expf(S * a0);
            float E2 = E1*E1, E4 = E2*E2, E8 = E4*E4;
            W[0]=E1;      W[1]=E2;      W[2]=E2*E1;   W[3]=E4;
            W[4]=E4*E1;   W[5]=E4*E2;   W[6]=E4*W[2]; W[7]=E8;
            W[8]=E8*E1;   W[9]=E8*E2;   W[10]=E8*W[2];W[11]=E8*E4;
            W[12]=E8*W[4];W[13]=E8*W[5];W[14]=E8*W[6];W[15]=E8*E8;
        } else {
#pragma unroll
            for (int n = 0; n < 16; n++) W[n] = __expf(S * a[n]);
        }
        size_t base = ((size_t)(bz * NCH + chunk) * DINNER + d) * 16;
#pragma unroll
        for (int q = 0; q < 4; q++) {
            *(float4*)(Hloc + base + q*4) = make_float4(h[q*4+0], h[q*4+1], h[q*4+2], h[q*4+3]);
            *(float4*)(Wp   + base + q*4) = make_float4(W[q*4+0], W[q*4+1], W[q*4+2], W[q*4+3]);
        }
    }
}

__global__ __launch_bounds__(256) void scan_combine(
    const float* __restrict__ Hloc, const float* __restrict__ Wp,
    float* __restrict__ Hin)
{
    int idx = blockIdx.x * 256 + threadIdx.x;
    int bz = idx / (DINNER * 16);
    int rest = idx % (DINNER * 16);
    float hin = 0.f;
#pragma unroll 4
    for (int k = 0; k < NCH; k++) {
        size_t o = (size_t)(bz * NCH + k) * (DINNER * 16) + rest;
        Hin[o] = hin;
        hin = fmaf(Wp[o], hin, Hloc[o]);
    }
}

// ---------------------------------------------------------------------------
extern "C" void kernel_launch(void* const* d_in, const int* in_sizes, int n_in,
                              void* d_out, int out_size, void* d_ws, size_t ws_size,
                              hipStream_t stream)
{
    const float* x        = (const float*)d_in[0];
    const float* in_nw    = (const float*)d_in[1];
    const float* in_nb    = (const float*)d_in[2];
    const float* ip_w     = (const float*)d_in[3];
    const float* ip_b     = (const float*)d_in[4];
    const float* f_in_w   = (const float*)d_in[5];
    const float* f_in_b   = (const float*)d_in[6];
    const float* f_conv_w = (const float*)d_in[7];
    const float* f_conv_b = (const float*)d_in[8];
    const float* f_xp_w   = (const float*)d_in[9];
    const float* f_dt_w   = (const float*)d_in[10];
    const float* f_dt_b   = (const float*)d_in[11];
    const float* f_A_log  = (const float*)d_in[12];
    const float* f_D      = (const float*)d_in[13];
    const float* f_out_w  = (const float*)d_in[14];
    const float* f_out_b  = (const float*)d_in[15];
    const float* b_in_w   = (const float*)d_in[16];
    const float* b_in_b   = (const float*)d_in[17];
    const float* b_conv_w = (const float*)d_in[18];
    const float* b_conv_b = (const float*)d_in[19];
    const float* b_xp_w   = (const float*)d_in[20];
    const float* b_dt_w   = (const float*)d_in[21];
    const float* b_dt_b   = (const float*)d_in[22];
    const float* b_A_log  = (const float*)d_in[23];
    const float* b_D      = (const float*)d_in[24];
    const float* b_out_w  = (const float*)d_in[25];
    const float* b_out_b  = (const float*)d_in[26];
    const float* op_w     = (const float*)d_in[27];
    const float* op_b     = (const float*)d_in[28];
    const float* norm_w   = (const float*)d_in[29];
    const float* norm_b   = (const float*)d_in[30];

    size_t off = 0;
    auto alloc = [&](size_t bytes) {
        void* p = (char*)d_ws + off;
        off += (bytes + 255) & ~(size_t)255;
        return p;
    };
    const size_t R = ROWS;
    ushort* xn_bf   = (ushort*)alloc(R * 768 * 2);
    ushort* xz_f_bf = (ushort*)alloc(R * 1536 * 2);
    ushort* xz_b_bf = (ushort*)alloc(R * 1536 * 2);
    ushort* xd64_f  = (ushort*)alloc(R * 64 * 2);
    ushort* xd64_b  = (ushort*)alloc(R * 64 * 2);
    ushort* dt_f    = (ushort*)alloc(R * 768 * 2);
    ushort* dt_b    = (ushort*)alloc(R * 768 * 2);
    ushort* y_f_bf  = (ushort*)alloc(R * 768 * 2);
    ushort* y_b_bf  = (ushort*)alloc(R * 768 * 2);
    float*  outraw  = (float*)alloc(R * 768 * 4);
    const size_t SCN = (size_t)4 * NCH * DINNER * 16;
    float* Hloc = (float*)alloc(SCN * 4);
    float* Wpb  = (float*)alloc(SCN * 4);
    float* Hin  = (float*)alloc(SCN * 4);
    ushort* Wt_fin = (ushort*)alloc((size_t)1536 * 384 * 2);
    ushort* Wt_bin = (ushort*)alloc((size_t)1536 * 384 * 2);
    ushort* Wt_op  = (ushort*)alloc((size_t)768 * 768 * 2);
    ushort* Wt_fxp = (ushort*)alloc((size_t)64 * 768 * 2);
    ushort* Wt_bxp = (ushort*)alloc((size_t)64 * 768 * 2);
    ushort* dtwT_f = (ushort*)alloc((size_t)768 * 64 * 2);
    ushort* dtwT_b = (ushort*)alloc((size_t)768 * 64 * 2);
    ushort* ipc    = (ushort*)alloc((size_t)768 * 768 * 2);
    ushort* fow    = (ushort*)alloc((size_t)768 * 384 * 2);
    ushort* bow    = (ushort*)alloc((size_t)768 * 384 * 2);
    ushort* WzF    = (ushort*)alloc((size_t)1536 * 768 * 2);
    ushort* WzB    = (ushort*)alloc((size_t)1536 * 768 * 2);
    ushort* WoF    = (ushort*)alloc((size_t)768 * 768 * 2);
    ushort* WoB    = (ushort*)alloc((size_t)768 * 768 * 2);
    float*  bzf    = (float*)alloc(1536 * 4);
    float*  bzb    = (float*)alloc(1536 * 4);
    float*  bo     = (float*)alloc(768 * 4);

    // ---- D1: prep (tcast + ln1) ----
    PrepArgs pa;
    int tile0 = 0, nd = 0;
    auto add = [&](const float* s, ushort* dst, int K, int N, int Kp, int Np,
                   int ldd, int mode) {
        pa.d[nd] = TD{s, dst, K, N, Kp, Np, ldd, tile0, Kp / 32, mode};
        tile0 += (Kp / 32) * (Np / 32);
        nd++;
    };
    add(f_in_w,  Wt_fin, 384, 1536, 384, 1536, 384, 0);
    add(b_in_w,  Wt_bin, 384, 1536, 384, 1536, 384, 0);
    add(op_w,    Wt_op,  768, 768,  768, 768,  768, 0);
    add(f_xp_w,  Wt_fxp, 768, 56,   768, 64,   768, 0);
    add(b_xp_w,  Wt_bxp, 768, 56,   768, 64,   768, 0);
    add(f_dt_w,  dtwT_f, 24,  768,  64,  768,  64,  0);  // zero-padded K 24->64
    add(b_dt_w,  dtwT_b, 24,  768,  64,  768,  64,  0);
    add(ip_w,    ipc,    768, 768,  768, 768,  768, 1);
    add(f_out_w, fow,    768, 384,  768, 384,  384, 1);
    add(b_out_w, bow,    768, 384,  768, 384,  384, 1);
    pa.ntc = tile0;
    for (int i = nd; i < 12; i++) pa.d[i].tile0 = 0x7fffffff;
    pa.x = x; pa.in_nw = in_nw; pa.in_nb = in_nb; pa.xn = xn_bf;
    hipLaunchKernelGGL(prep_kernel, dim3(tile0 + ROWS), dim3(256), 0, stream, pa);

    // ---- D2: weight fusion ----
    WfArgs wa;
    wa.fin = Wt_fin; wa.bin = Wt_bin; wa.opT = Wt_op;
    wa.ipc = ipc; wa.fow = fow; wa.bow = bow;
    wa.WzF = WzF; wa.WzB = WzB; wa.WoF = WoF; wa.WoB = WoB;
    wa.ip_b = ip_b; wa.f_in_b = f_in_b; wa.b_in_b = b_in_b;
    wa.f_out_b = f_out_b; wa.b_out_b = b_out_b; wa.op_b = op_b;
    wa.f_in_w32 = f_in_w; wa.b_in_w32 = b_in_w; wa.op_w32 = op_w;
    wa.bzf = bzf; wa.bzb = bzb; wa.bo = bo;
    hipLaunchKernelGGL(wfuse_kernel, dim3(447), dim3(256), 0, stream, wa);

    // ---- D3: xz_{f,b} = xn @ Wz + bz (K=768, ip folded in) ----
    hipLaunchKernelGGL((mfma_gemm_k<128, 128, true>), dim3(12, 32, 2), dim3(256), 0, stream,
                       xn_bf, xn_bf, 768, WzF, WzB, 768, bzf, bzb,
                       (void*)xz_f_bf, (void*)xz_b_bf, 1536, 1536, 768);

    // ---- D4: fused conv+silu -> xd64 -> dt (replaces 3 dispatches) ----
    hipLaunchKernelGGL(xddt_kernel, dim3(1, ROWS / 64, 2), dim3(256), 0, stream,
                       xz_f_bf, xz_b_bf, f_conv_w, f_conv_b, b_conv_w, b_conv_b,
                       Wt_fxp, Wt_bxp, dtwT_f, dtwT_b, f_dt_b, b_dt_b,
                       xd64_f, xd64_b, dt_f, dt_b);

    // ---- D5/D6/D7: chunked selective scan (conv inline) ----
    hipLaunchKernelGGL((scan_chunk_kernel<false>), dim3(DINNER / 256, NCH, 4), dim3(256), 0, stream,
                       dt_f, xd64_f, xz_f_bf, f_conv_w, f_conv_b, f_A_log, f_D,
                       dt_b, xd64_b, xz_b_bf, b_conv_w, b_conv_b, b_A_log, b_D,
                       Hloc, Wpb, (const float*)nullptr, (ushort*)nullptr, (ushort*)nullptr);
    hipLaunchKernelGGL(scan_combine, dim3(4 * DINNER * 16 / 256), dim3(256), 0, stream,
                       Hloc, Wpb, Hin);
    hipLaunchKernelGGL((scan_chunk_kernel<true>), dim3(DINNER / 256, NCH, 4), dim3(256), 0, stream,
                       dt_f, xd64_f, xz_f_bf, f_conv_w, f_conv_b, f_A_log, f_D,
                       dt_b, xd64_b, xz_b_bf, b_conv_w, b_conv_b, b_A_log, b_D,
                       (float*)nullptr, (float*)nullptr, Hin, y_f_bf, y_b_bf);

    // ---- D8: outraw = y_f @ WoF + y_b @ WoB + bo ----
    hipLaunchKernelGGL((outop_kernel<128, 64>), dim3(12, 32), dim3(256), 0, stream,
                       y_f_bf, WoF, y_b_bf, WoB, bo, outraw, 768, 768, 768, 768, 768);

    // ---- D9: final layernorm(residual + out) ----
    hipLaunchKernelGGL(ln2_kernel, dim3(ROWS), dim3(256), 0, stream,
                       x, outraw, norm_w, norm_b, (float*)d_out);
}

// Round 11
// 342.398 us; speedup vs baseline: 1.1176x; 1.1176x over previous
//
#include <hip/hip_runtime.h>
#include <hip/hip_bf16.h>
#include <math.h>
#include <type_traits>

#define BATCH 2
#define SEQ   2048
#define DMODEL 768
#define DIN   384
#define DINNER 768
#define DSTATE 16
#define DTRANK 24
#define ROWS  (BATCH*SEQ)   // 4096
#define NCH   64            // time chunks for the scan
#define CLEN  (SEQ/NCH)     // 32 steps per chunk

using short8  = __attribute__((ext_vector_type(8))) short;
using floatx4 = __attribute__((ext_vector_type(4))) float;

__device__ __forceinline__ ushort f2bf(float f) {
    union { float f; uint u; } v; v.f = f;
    uint r = (v.u + 0x7fffu + ((v.u >> 16) & 1u)) >> 16;
    return (ushort)r;
}
__device__ __forceinline__ float bf2f(ushort h) {
    union { uint u; float f; } v; v.u = ((uint)h) << 16;
    return v.f;
}
__device__ __forceinline__ void async16(const ushort* g, ushort* l) {
    __builtin_amdgcn_global_load_lds(
        (const __attribute__((address_space(1))) void*)g,
        (__attribute__((address_space(3))) void*)l,
        16, 0, 0);
}
// softplus via fast HW transcendentals (v_exp_f32 + v_log_f32)
__device__ __forceinline__ float softplus_fast(float v) {
    if (v > 20.f) return v;
    float e = __expf(-fabsf(v));
    return fmaxf(v, 0.f) + __logf(1.f + e);
}

// ---------------------------------------------------------------------------
// MFMA GEMM building blocks (m97 staging, BK=64, XOR-swizzled LDS).
// [R7: conflicts 7.1M -> 0]
// ---------------------------------------------------------------------------
template<int TM, int TN> struct GemmShT { ushort lA[TM * 64]; ushort lB[TN * 64]; };

template<int TM, int TN>
__device__ __forceinline__ void gemm_accum(
    const ushort* __restrict__ A, int lda,
    const ushort* __restrict__ Bt, int ldb,
    int K, int m0, int n0, GemmShT<TM, TN>& sh,
    floatx4 (&acc)[TM / 32][TN / 32])
{
    constexpr int WM = TM / 2, WN = TN / 2;
    constexpr int MT = WM / 16, NT = WN / 16;
    constexpr int AI = TM / 32, BI = TN / 32;
    const int tid = threadIdx.x;
    const int wave = tid >> 6, lane = tid & 63;
    const int wm = wave >> 1, wn = wave & 1;
    const int quad = lane >> 4, l16 = lane & 15;
    const int lrow = lane >> 3;                      // 8 rows per 1KB wave-store
    const int lcol = ((lane & 7) ^ (lane >> 3)) * 8; // XOR-swizzled source granule

    for (int k0 = 0; k0 < K; k0 += 64) {
#pragma unroll
        for (int i = 0; i < AI; i++) {
            int rb = (wave * AI + i) * 8;
            async16(A + (size_t)(m0 + rb + lrow) * lda + k0 + lcol, &sh.lA[rb * 64]);
        }
#pragma unroll
        for (int i = 0; i < BI; i++) {
            int rb = (wave * BI + i) * 8;
            async16(Bt + (size_t)(n0 + rb + lrow) * ldb + k0 + lcol, &sh.lB[rb * 64]);
        }
        __syncthreads();
#pragma unroll
        for (int ks = 0; ks < 2; ks++) {
            short8 af[MT], bf[NT];
#pragma unroll
            for (int i = 0; i < MT; i++) {
                int row = wm * WM + i * 16 + l16;
                af[i] = *(const short8*)&sh.lA[row * 64 + ((ks * 4 + quad) ^ (row & 7)) * 8];
            }
#pragma unroll
            for (int j = 0; j < NT; j++) {
                int row = wn * WN + j * 16 + l16;
                bf[j] = *(const short8*)&sh.lB[row * 64 + ((ks * 4 + quad) ^ (row & 7)) * 8];
            }
#pragma unroll
            for (int i = 0; i < MT; i++)
#pragma unroll
                for (int j = 0; j < NT; j++)
                    acc[i][j] = __builtin_amdgcn_mfma_f32_16x16x32_bf16(af[i], bf[j], acc[i][j], 0, 0, 0);
        }
        __syncthreads();
    }
}

template<int TM, int TN, bool OUT_BF>
__device__ __forceinline__ void gemm_epilogue(
    const float* __restrict__ bias, void* __restrict__ C, int ldc, int N,
    int m0, int n0, floatx4 (&acc)[TM / 32][TN / 32])
{
    constexpr int WM = TM / 2, WN = TN / 2;
    constexpr int MT = WM / 16, NT = WN / 16;
    const int tid = threadIdx.x;
    const int wave = tid >> 6, lane = tid & 63;
    const int wm = wave >> 1, wn = wave & 1;
    const int quad = lane >> 4, l16 = lane & 15;
#pragma unroll
    for (int i = 0; i < MT; i++) {
#pragma unroll
        for (int j = 0; j < NT; j++) {
            int row = m0 + wm * WM + i * 16 + quad * 4;
            int col = n0 + wn * WN + j * 16 + l16;
            if (col < N) {
                float bv = bias ? bias[col] : 0.f;
#pragma unroll
                for (int r = 0; r < 4; r++) {
                    float v = acc[i][j][r] + bv;
                    if (OUT_BF) ((ushort*)C)[(size_t)(row + r) * ldc + col] = f2bf(v);
                    else        ((float*)C)[(size_t)(row + r) * ldc + col] = v;
                }
            }
        }
    }
}

// Generic single-pair GEMM kernel; grid.z selects f/b operand sets.
template<int TM, int TN, bool OUT_BF>
__global__ __launch_bounds__(256) void mfma_gemm_k(
    const ushort* __restrict__ A0, const ushort* __restrict__ A1, int lda,
    const ushort* __restrict__ B0, const ushort* __restrict__ B1, int ldb,
    const float* __restrict__ bias0, const float* __restrict__ bias1,
    void* __restrict__ C0, void* __restrict__ C1, int ldc, int N, int K)
{
    __shared__ GemmShT<TM, TN> sh;
    const ushort* A  = blockIdx.z ? A1 : A0;
    const ushort* Bt = blockIdx.z ? B1 : B0;
    const float* bias = blockIdx.z ? bias1 : bias0;
    void* C = blockIdx.z ? C1 : C0;
    floatx4 acc[TM / 32][TN / 32];
#pragma unroll
    for (int i = 0; i < TM / 32; i++)
#pragma unroll
        for (int j = 0; j < TN / 32; j++)
            acc[i][j] = (floatx4){0.f, 0.f, 0.f, 0.f};
    int m0 = blockIdx.y * TM, n0 = blockIdx.x * TN;
    gemm_accum<TM, TN>(A, lda, Bt, ldb, K, m0, n0, sh, acc);
    gemm_epilogue<TM, TN, OUT_BF>(bias, C, ldc, N, m0, n0, acc);
}

// dt = softplus(xd64 @ dtwT^T + dt_b). K=64 (zero-padded rows annihilate
// the B/C columns). Fast-softplus epilogue, bf16 out.
__global__ __launch_bounds__(256) void dt_kernel(
    const ushort* __restrict__ xdf, const ushort* __restrict__ xdb,
    const ushort* __restrict__ dtwTf, const ushort* __restrict__ dtwTb,
    const float* __restrict__ dtbf, const float* __restrict__ dtbb,
    ushort* __restrict__ dtf, ushort* __restrict__ dtb)
{
    constexpr int TM = 128, TN = 64;
    __shared__ GemmShT<TM, TN> sh;
    const ushort* A  = blockIdx.z ? xdb : xdf;
    const ushort* Bt = blockIdx.z ? dtwTb : dtwTf;
    const float* bias = blockIdx.z ? dtbb : dtbf;
    ushort* C = blockIdx.z ? dtb : dtf;
    floatx4 acc[4][2];
#pragma unroll
    for (int i = 0; i < 4; i++)
#pragma unroll
        for (int j = 0; j < 2; j++)
            acc[i][j] = (floatx4){0.f, 0.f, 0.f, 0.f};
    int m0 = blockIdx.y * TM, n0 = blockIdx.x * TN;
    gemm_accum<TM, TN>(A, 64, Bt, 64, 64, m0, n0, sh, acc);
    const int tid = threadIdx.x;
    const int wave = tid >> 6, lane = tid & 63;
    const int wm = wave >> 1, wn = wave & 1;
    const int quad = lane >> 4, l16 = lane & 15;
#pragma unroll
    for (int i = 0; i < 4; i++) {
#pragma unroll
        for (int j = 0; j < 2; j++) {
            int row = m0 + wm * 64 + i * 16 + quad * 4;
            int col = n0 + wn * 32 + j * 16 + l16;
            float bv = bias[col];
#pragma unroll
            for (int r = 0; r < 4; r++)
                C[(size_t)(row + r) * 768 + col] = f2bf(softplus_fast(acc[i][j][r] + bv));
        }
    }
}

// Dual-A GEMM: C = A0@B0^T + A1@B1^T + bias (fused out+op projection).
// 64x64 tiles -> 768 blocks (3/CU) [R11: was 128x64, 384 blocks, 1.5/CU]
template<int TM, int TN>
__global__ __launch_bounds__(256) void outop_kernel(
    const ushort* __restrict__ A0, const ushort* __restrict__ B0,
    const ushort* __restrict__ A1, const ushort* __restrict__ B1,
    const float* __restrict__ bias, float* __restrict__ C,
    int lda, int ldb, int ldc, int N, int K)
{
    __shared__ GemmShT<TM, TN> sh;
    floatx4 acc[TM / 32][TN / 32];
#pragma unroll
    for (int i = 0; i < TM / 32; i++)
#pragma unroll
        for (int j = 0; j < TN / 32; j++)
            acc[i][j] = (floatx4){0.f, 0.f, 0.f, 0.f};
    int m0 = blockIdx.y * TM, n0 = blockIdx.x * TN;
    gemm_accum<TM, TN>(A0, lda, B0, ldb, K, m0, n0, sh, acc);
    gemm_accum<TM, TN>(A1, lda, B1, ldb, K, m0, n0, sh, acc);
    gemm_epilogue<TM, TN, false>(bias, (void*)C, ldc, N, m0, n0, acc);
}

// ---------------------------------------------------------------------------
// LayerNorm row helper (+ standalone kernel for the final LN).
// ---------------------------------------------------------------------------
struct LnSh { float ss[4]; float ssq[4]; float m; float rs; };

template<bool OUT_BF>
__device__ __forceinline__ void ln_row(
    int row, const float* __restrict__ x, const float* __restrict__ res,
    const float* __restrict__ w, const float* __restrict__ b,
    void* __restrict__ out, LnSh& sh)
{
    int tid = threadIdx.x;
    const float* xr = x + (size_t)row * DMODEL;
    const float* rr = res ? res + (size_t)row * DMODEL : nullptr;
    float v[3];
    float s = 0.f, sq = 0.f;
#pragma unroll
    for (int j = 0; j < 3; j++) {
        int i = tid + j * 256;
        float val = xr[i];
        if (rr) val += rr[i];
        v[j] = val; s += val; sq += val * val;
    }
#pragma unroll
    for (int off = 32; off; off >>= 1) {
        s  += __shfl_down(s,  off);
        sq += __shfl_down(sq, off);
    }
    int wid = tid >> 6;
    if ((tid & 63) == 0) { sh.ss[wid] = s; sh.ssq[wid] = sq; }
    __syncthreads();
    if (tid == 0) {
        float S  = sh.ss[0] + sh.ss[1] + sh.ss[2] + sh.ss[3];
        float SQ = sh.ssq[0] + sh.ssq[1] + sh.ssq[2] + sh.ssq[3];
        float m  = S * (1.0f / DMODEL);
        float var = SQ * (1.0f / DMODEL) - m * m;
        sh.m = m;
        sh.rs = rsqrtf(var + 1e-5f);
    }
    __syncthreads();
    float m = sh.m, rs = sh.rs;
#pragma unroll
    for (int j = 0; j < 3; j++) {
        int i = tid + j * 256;
        float r = (v[j] - m) * rs * w[i] + b[i];
        if (OUT_BF) ((ushort*)out)[(size_t)row * DMODEL + i] = f2bf(r);
        else        ((float*)out)[(size_t)row * DMODEL + i] = r;
    }
}

__global__ __launch_bounds__(256) void ln2_kernel(
    const float* __restrict__ x, const float* __restrict__ res,
    const float* __restrict__ w, const float* __restrict__ b,
    float* __restrict__ out)
{
    __shared__ LnSh sh;
    ln_row<false>(blockIdx.x, x, res, w, b, (void*)out, sh);
}

// ---------------------------------------------------------------------------
// Prep: weight transpose/cast with zero-padding + input LN.
// ---------------------------------------------------------------------------
struct TD { const float* src; ushort* dst; int K, N, Kp, Np, ldd, tile0, tkp, mode; };
struct PrepArgs {
    TD d[12];
    int ntc;
    const float *x, *in_nw, *in_nb;
    ushort* xn;
};

__global__ __launch_bounds__(256) void prep_kernel(PrepArgs p)
{
    __shared__ union { float tile[32][33]; LnSh l; } sh;
    int bi = blockIdx.x;
    if (bi < p.ntc) {
        int i = 0;
        while (i < 11 && bi >= p.d[i + 1].tile0) i++;
        TD t = p.d[i];
        int local = bi - t.tile0;
        int tki = local % t.tkp, tn = local / t.tkp;
        int k0 = tki * 32, n0 = tn * 32;
        if (t.mode == 0) {
            int tx = threadIdx.x & 31, ty = threadIdx.x >> 5;
#pragma unroll
            for (int r = ty; r < 32; r += 8) {
                int k = k0 + r, n = n0 + tx;
                sh.tile[r][tx] = (k < t.K && n < t.N) ? t.src[(size_t)k * t.N + n] : 0.f;
            }
            __syncthreads();
#pragma unroll
            for (int r = ty; r < 32; r += 8) {
                int n = n0 + r, k = k0 + tx;
                t.dst[(size_t)n * t.ldd + k] = f2bf(sh.tile[tx][r]);
            }
        } else {
#pragma unroll
            for (int e = threadIdx.x; e < 1024; e += 256) {
                int r = e >> 5, c = e & 31;
                int k = k0 + r, n = n0 + c;
                float v = (k < t.K && n < t.N) ? t.src[(size_t)k * t.N + n] : 0.f;
                t.dst[(size_t)k * t.ldd + n] = f2bf(v);
            }
        }
    } else {
        ln_row<true>(bi - p.ntc, p.x, (const float*)nullptr, p.in_nw, p.in_nb,
                     (void*)p.xn, sh.l);
    }
}

// ---------------------------------------------------------------------------
// Weight-fusion dispatch: GEMV blocks first (ids 0..14, unrolled x16), then
// 864 GEMM tiles of 64x64 (R11: was 432x 128x64 at 1.7 blk/CU).
// ---------------------------------------------------------------------------
struct WfArgs {
    const ushort *fin, *bin, *opT, *ipc, *fow, *bow;
    ushort *WzF, *WzB, *WoF, *WoB;
    const float *ip_b, *f_in_b, *b_in_b, *f_out_b, *b_out_b, *op_b;
    const float *f_in_w32, *b_in_w32, *op_w32;
    float *bzf, *bzb, *bo;
};

__global__ __launch_bounds__(256) void wfuse_kernel(WfArgs p)
{
    __shared__ GemmShT<64, 64> sh;
    int t = blockIdx.x;
    if (t < 6) {                   // bz_f
        int n = t * 256 + threadIdx.x;
        float acc = p.f_in_b[n];
#pragma unroll 16
        for (int j = 0; j < 384; j++)
            acc = fmaf(p.ip_b[j], p.f_in_w32[(size_t)j * 1536 + n], acc);
        p.bzf[n] = acc;
    } else if (t < 12) {           // bz_b
        int n = (t - 6) * 256 + threadIdx.x;
        float acc = p.b_in_b[n];
#pragma unroll 16
        for (int j = 0; j < 384; j++)
            acc = fmaf(p.ip_b[384 + j], p.b_in_w32[(size_t)j * 1536 + n], acc);
        p.bzb[n] = acc;
    } else if (t < 15) {           // bo
        int n = (t - 12) * 256 + threadIdx.x;
        float acc = p.op_b[n];
#pragma unroll 16
        for (int j = 0; j < 384; j++)
            acc = fmaf(p.f_out_b[j], p.op_w32[(size_t)j * 768 + n], acc);
#pragma unroll 16
        for (int j = 0; j < 384; j++)
            acc = fmaf(p.b_out_b[j], p.op_w32[(size_t)(384 + j) * 768 + n], acc);
        p.bo[n] = acc;
    } else {
        int g = t - 15;
        const ushort *A, *Bt; ushort* C; int lda, ldb, m0, n0;
        if (g < 288)      { A = p.fin;       lda = 384; Bt = p.ipc;       ldb = 768; C = p.WzF; int u = g;       m0 = (u / 12) * 64; n0 = (u % 12) * 64; }
        else if (g < 576) { A = p.bin;       lda = 384; Bt = p.ipc + 384; ldb = 768; C = p.WzB; int u = g - 288; m0 = (u / 12) * 64; n0 = (u % 12) * 64; }
        else if (g < 720) { A = p.opT;       lda = 768; Bt = p.fow;       ldb = 384; C = p.WoF; int u = g - 576; m0 = (u / 12) * 64; n0 = (u % 12) * 64; }
        else              { A = p.opT + 384; lda = 768; Bt = p.bow;       ldb = 384; C = p.WoB; int u = g - 720; m0 = (u / 12) * 64; n0 = (u % 12) * 64; }
        floatx4 acc[2][2];
#pragma unroll
        for (int i = 0; i < 2; i++)
#pragma unroll
            for (int j = 0; j < 2; j++)
                acc[i][j] = (floatx4){0.f, 0.f, 0.f, 0.f};
        gemm_accum<64, 64>(A, lda, Bt, ldb, 384, m0, n0, sh, acc);
        gemm_epilogue<64, 64, true>((const float*)nullptr, (void*)C, 768, 768, m0, n0, acc);
    }
}

// ---------------------------------------------------------------------------
// Causal conv1d (K=4) + SiLU, one element/thread, float4 cw.
// ---------------------------------------------------------------------------
__global__ __launch_bounds__(256) void conv_silu_kernel(
    const ushort* __restrict__ xzf, const ushort* __restrict__ xzb,
    const float* __restrict__ cwf, const float* __restrict__ cbf,
    const float* __restrict__ cwb, const float* __restrict__ cbb,
    ushort* __restrict__ outf, ushort* __restrict__ outb)
{
    int rev = blockIdx.y;
    const ushort* xz = rev ? xzb : xzf;
    const float* cw = rev ? cwb : cwf;
    const float* cb = rev ? cbb : cbf;
    ushort* out = rev ? outb : outf;

    int idx = blockIdx.x * 256 + threadIdx.x;
    int d = idx % DINNER;
    int row = idx / DINNER;
    int t = row & (SEQ - 1), b = row >> 11;
    float4 w4 = *(const float4*)&cw[d * 4];
    float wk[4] = {w4.x, w4.y, w4.z, w4.w};
    float acc = cb[d];
#pragma unroll
    for (int k = 0; k < 4; k++) {
        int ts = rev ? (t + 3 - k) : (t - 3 + k);
        if (ts >= 0 && ts < SEQ)
            acc = fmaf(wk[k], bf2f(xz[((size_t)(b * SEQ + ts)) * 1536 + d]), acc);
    }
    float sig = 1.f / (1.f + __expf(-acc));
    out[idx] = f2bf(acc * sig);
}

// ---------------------------------------------------------------------------
// Chunked selective scan (NCH=64, CLEN=32). dt bf16; B/C from bf16 xd64
// (wave-uniform). Unroll 4 for deeper load pipelining (R11).
// ---------------------------------------------------------------------------
template<bool FULL>
__global__ __launch_bounds__(256) void scan_chunk_kernel(
    const ushort* __restrict__ dtf, const ushort* __restrict__ xcf,
    const ushort* __restrict__ xdf, const ushort* __restrict__ xzf,
    const float* __restrict__ Alf, const float* __restrict__ Dff,
    const ushort* __restrict__ dtb, const ushort* __restrict__ xcb,
    const ushort* __restrict__ xdb, const ushort* __restrict__ xzb,
    const float* __restrict__ Alb, const float* __restrict__ Dbb,
    float* __restrict__ Hloc, float* __restrict__ Wp,
    const float* __restrict__ Hin,
    ushort* __restrict__ yf, ushort* __restrict__ yb)
{
    const int d     = blockIdx.x * 256 + threadIdx.x;
    const int chunk = blockIdx.y;
    const int bz    = blockIdx.z;
    const int dir   = bz >> 1;
    const int bat   = bz & 1;

    const ushort* dt = dir ? dtb : dtf;
    const ushort* xc = dir ? xcb : xcf;
    const ushort* xd = dir ? xdb : xdf;
    const ushort* xz = dir ? xzb : xzf;
    const float*  Al = dir ? Alb : Alf;
    const float*  Dp = dir ? Dbb : Dff;
    ushort* yo = dir ? yb : yf;

    float a[16];
    {
        const float4* Ap = (const float4*)(Al + (size_t)d * 16);
#pragma unroll
        for (int q = 0; q < 4; q++) {
            float4 v = Ap[q];
            a[q*4+0] = -__expf(v.x); a[q*4+1] = -__expf(v.y);
            a[q*4+2] = -__expf(v.z); a[q*4+3] = -__expf(v.w);
        }
    }
    const float a0 = a[0];
    bool fast = true;
#pragma unroll
    for (int n = 0; n < 16; n++) {
        float ideal = a0 * (float)(n + 1);
        fast = fast && (fabsf(a[n] - ideal) <= 1e-4f * fabsf(ideal) + 1e-7f);
    }

    float h[16];
    if (FULL) {
        size_t base = ((size_t)(bz * NCH + chunk) * DINNER + d) * 16;
#pragma unroll
        for (int q = 0; q < 4; q++) {
            float4 v = *(const float4*)(Hin + base + q * 4);
            h[q*4+0] = v.x; h[q*4+1] = v.y; h[q*4+2] = v.z; h[q*4+3] = v.w;
        }
    } else {
#pragma unroll
        for (int n = 0; n < 16; n++) h[n] = 0.f;
    }

    const float Dd = FULL ? Dp[d] : 0.f;
    float S = 0.f;

    auto run = [&](auto FASTC) {
        constexpr bool FAST = decltype(FASTC)::value;
#pragma unroll 4
        for (int i = 0; i < CLEN; i++) {
            int tl = chunk * CLEN + i;
            int t  = dir ? (SEQ - 1 - tl) : tl;
            size_t r = (size_t)(bat * SEQ + t);
            float dtv = bf2f(dt[r * DINNER + d]);
            float xv  = bf2f(xc[r * DINNER + d]);
            const ushort* bp = xd + r * 64 + DTRANK;   // wave-uniform
            short8 b0 = *(const short8*)(bp);
            short8 b1 = *(const short8*)(bp + 8);
            float Bv[16];
#pragma unroll
            for (int n = 0; n < 8; n++) {
                Bv[n]     = bf2f((ushort)b0[n]);
                Bv[8 + n] = bf2f((ushort)b1[n]);
            }
            float w[16];
            if (FAST) {
                float e1 = __expf(dtv * a0);
                float e2 = e1*e1, e4 = e2*e2, e8 = e4*e4;
                w[0]=e1;      w[1]=e2;      w[2]=e2*e1;   w[3]=e4;
                w[4]=e4*e1;   w[5]=e4*e2;   w[6]=e4*w[2]; w[7]=e8;
                w[8]=e8*e1;   w[9]=e8*e2;   w[10]=e8*w[2];w[11]=e8*e4;
                w[12]=e8*w[4];w[13]=e8*w[5];w[14]=e8*w[6];w[15]=e8*e8;
            } else {
#pragma unroll
                for (int n = 0; n < 16; n++) w[n] = __expf(dtv * a[n]);
            }
            float bx = dtv * xv;
#pragma unroll
            for (int n = 0; n < 16; n++)
                h[n] = fmaf(w[n], h[n], bx * Bv[n]);
            S += dtv;
            if (FULL) {
                short8 c0 = *(const short8*)(bp + 16);
                short8 c1 = *(const short8*)(bp + 24);
                float Cv[16];
#pragma unroll
                for (int n = 0; n < 8; n++) {
                    Cv[n]     = bf2f((ushort)c0[n]);
                    Cv[8 + n] = bf2f((ushort)c1[n]);
                }
                float y = 0.f;
#pragma unroll
                for (int n = 0; n < 16; n++) y = fmaf(h[n], Cv[n], y);
                float zv = bf2f(xz[r * 1536 + DINNER + d]);
                float sig = 1.f / (1.f + __expf(-zv));
                yo[r * DINNER + d] = f2bf((y + xv * Dd) * (zv * sig));
            }
        }
    };
    if (fast) run(std::true_type{}); else run(std::false_type{});

    if (!FULL) {
        float W[16];
        if (fast) {
            float E1 = __expf(S * a0);
            float E2 = E1*E1, E4 = E2*E2, E8 = E4*E4;
            W[0]=E1;      W[1]=E2;      W[2]=E2*E1;   W[3]=E4;
            W[4]=E4*E1;   W[5]=E4*E2;   W[6]=E4*W[2]; W[7]=E8;
            W[8]=E8*E1;   W[9]=E8*E2;   W[10]=E8*W[2];W[11]=E8*E4;
            W[12]=E8*W[4];W[13]=E8*W[5];W[14]=E8*W[6];W[15]=E8*E8;
        } else {
#pragma unroll
            for (int n = 0; n < 16; n++) W[n] = __expf(S * a[n]);
        }
        size_t base = ((size_t)(bz * NCH + chunk) * DINNER + d) * 16;
#pragma unroll
        for (int q = 0; q < 4; q++) {
            *(float4*)(Hloc + base + q*4) = make_float4(h[q*4+0], h[q*4+1], h[q*4+2], h[q*4+3]);
            *(float4*)(Wp   + base + q*4) = make_float4(W[q*4+0], W[q*4+1], W[q*4+2], W[q*4+3]);
        }
    }
}

__global__ __launch_bounds__(256) void scan_combine(
    const float* __restrict__ Hloc, const float* __restrict__ Wp,
    float* __restrict__ Hin)
{
    int idx = blockIdx.x * 256 + threadIdx.x;
    int bz = idx / (DINNER * 16);
    int rest = idx % (DINNER * 16);
    float hin = 0.f;
#pragma unroll 16
    for (int k = 0; k < NCH; k++) {
        size_t o = (size_t)(bz * NCH + k) * (DINNER * 16) + rest;
        Hin[o] = hin;
        hin = fmaf(Wp[o], hin, Hloc[o]);
    }
}

// ---------------------------------------------------------------------------
extern "C" void kernel_launch(void* const* d_in, const int* in_sizes, int n_in,
                              void* d_out, int out_size, void* d_ws, size_t ws_size,
                              hipStream_t stream)
{
    const float* x        = (const float*)d_in[0];
    const float* in_nw    = (const float*)d_in[1];
    const float* in_nb    = (const float*)d_in[2];
    const float* ip_w     = (const float*)d_in[3];
    const float* ip_b     = (const float*)d_in[4];
    const float* f_in_w   = (const float*)d_in[5];
    const float* f_in_b   = (const float*)d_in[6];
    const float* f_conv_w = (const float*)d_in[7];
    const float* f_conv_b = (const float*)d_in[8];
    const float* f_xp_w   = (const float*)d_in[9];
    const float* f_dt_w   = (const float*)d_in[10];
    const float* f_dt_b   = (const float*)d_in[11];
    const float* f_A_log  = (const float*)d_in[12];
    const float* f_D      = (const float*)d_in[13];
    const float* f_out_w  = (const float*)d_in[14];
    const float* f_out_b  = (const float*)d_in[15];
    const float* b_in_w   = (const float*)d_in[16];
    const float* b_in_b   = (const float*)d_in[17];
    const float* b_conv_w = (const float*)d_in[18];
    const float* b_conv_b = (const float*)d_in[19];
    const float* b_xp_w   = (const float*)d_in[20];
    const float* b_dt_w   = (const float*)d_in[21];
    const float* b_dt_b   = (const float*)d_in[22];
    const float* b_A_log  = (const float*)d_in[23];
    const float* b_D      = (const float*)d_in[24];
    const float* b_out_w  = (const float*)d_in[25];
    const float* b_out_b  = (const float*)d_in[26];
    const float* op_w     = (const float*)d_in[27];
    const float* op_b     = (const float*)d_in[28];
    const float* norm_w   = (const float*)d_in[29];
    const float* norm_b   = (const float*)d_in[30];

    size_t off = 0;
    auto alloc = [&](size_t bytes) {
        void* p = (char*)d_ws + off;
        off += (bytes + 255) & ~(size_t)255;
        return p;
    };
    const size_t R = ROWS;
    ushort* xn_bf   = (ushort*)alloc(R * 768 * 2);
    ushort* xz_f_bf = (ushort*)alloc(R * 1536 * 2);
    ushort* xz_b_bf = (ushort*)alloc(R * 1536 * 2);
    ushort* xc_f_bf = (ushort*)alloc(R * 768 * 2);
    ushort* xc_b_bf = (ushort*)alloc(R * 768 * 2);
    ushort* xd64_f  = (ushort*)alloc(R * 64 * 2);
    ushort* xd64_b  = (ushort*)alloc(R * 64 * 2);
    ushort* dt_f    = (ushort*)alloc(R * 768 * 2);
    ushort* dt_b    = (ushort*)alloc(R * 768 * 2);
    ushort* y_f_bf  = (ushort*)alloc(R * 768 * 2);
    ushort* y_b_bf  = (ushort*)alloc(R * 768 * 2);
    float*  outraw  = (float*)alloc(R * 768 * 4);
    const size_t SCN = (size_t)4 * NCH * DINNER * 16;
    float* Hloc = (float*)alloc(SCN * 4);
    float* Wpb  = (float*)alloc(SCN * 4);
    float* Hin  = (float*)alloc(SCN * 4);
    ushort* Wt_fin = (ushort*)alloc((size_t)1536 * 384 * 2);
    ushort* Wt_bin = (ushort*)alloc((size_t)1536 * 384 * 2);
    ushort* Wt_op  = (ushort*)alloc((size_t)768 * 768 * 2);
    ushort* Wt_fxp = (ushort*)alloc((size_t)64 * 768 * 2);
    ushort* Wt_bxp = (ushort*)alloc((size_t)64 * 768 * 2);
    ushort* dtwT_f = (ushort*)alloc((size_t)768 * 64 * 2);
    ushort* dtwT_b = (ushort*)alloc((size_t)768 * 64 * 2);
    ushort* ipc    = (ushort*)alloc((size_t)768 * 768 * 2);
    ushort* fow    = (ushort*)alloc((size_t)768 * 384 * 2);
    ushort* bow    = (ushort*)alloc((size_t)768 * 384 * 2);
    ushort* WzF    = (ushort*)alloc((size_t)1536 * 768 * 2);
    ushort* WzB    = (ushort*)alloc((size_t)1536 * 768 * 2);
    ushort* WoF    = (ushort*)alloc((size_t)768 * 768 * 2);
    ushort* WoB    = (ushort*)alloc((size_t)768 * 768 * 2);
    float*  bzf    = (float*)alloc(1536 * 4);
    float*  bzb    = (float*)alloc(1536 * 4);
    float*  bo     = (float*)alloc(768 * 4);

    // ---- D1: prep (tcast + ln1) ----
    PrepArgs pa;
    int tile0 = 0, nd = 0;
    auto add = [&](const float* s, ushort* dst, int K, int N, int Kp, int Np,
                   int ldd, int mode) {
        pa.d[nd] = TD{s, dst, K, N, Kp, Np, ldd, tile0, Kp / 32, mode};
        tile0 += (Kp / 32) * (Np / 32);
        nd++;
    };
    add(f_in_w,  Wt_fin, 384, 1536, 384, 1536, 384, 0);
    add(b_in_w,  Wt_bin, 384, 1536, 384, 1536, 384, 0);
    add(op_w,    Wt_op,  768, 768,  768, 768,  768, 0);
    add(f_xp_w,  Wt_fxp, 768, 56,   768, 64,   768, 0);
    add(b_xp_w,  Wt_bxp, 768, 56,   768, 64,   768, 0);
    add(f_dt_w,  dtwT_f, 24,  768,  64,  768,  64,  0);  // zero-padded K 24->64
    add(b_dt_w,  dtwT_b, 24,  768,  64,  768,  64,  0);
    add(ip_w,    ipc,    768, 768,  768, 768,  768, 1);
    add(f_out_w, fow,    768, 384,  768, 384,  384, 1);
    add(b_out_w, bow,    768, 384,  768, 384,  384, 1);
    pa.ntc = tile0;
    for (int i = nd; i < 12; i++) pa.d[i].tile0 = 0x7fffffff;
    pa.x = x; pa.in_nw = in_nw; pa.in_nb = in_nb; pa.xn = xn_bf;
    hipLaunchKernelGGL(prep_kernel, dim3(tile0 + ROWS), dim3(256), 0, stream, pa);

    // ---- D2: weight fusion (GEMV blocks first, 64x64 GEMM tiles) ----
    WfArgs wa;
    wa.fin = Wt_fin; wa.bin = Wt_bin; wa.opT = Wt_op;
    wa.ipc = ipc; wa.fow = fow; wa.bow = bow;
    wa.WzF = WzF; wa.WzB = WzB; wa.WoF = WoF; wa.WoB = WoB;
    wa.ip_b = ip_b; wa.f_in_b = f_in_b; wa.b_in_b = b_in_b;
    wa.f_out_b = f_out_b; wa.b_out_b = b_out_b; wa.op_b = op_b;
    wa.f_in_w32 = f_in_w; wa.b_in_w32 = b_in_w; wa.op_w32 = op_w;
    wa.bzf = bzf; wa.bzb = bzb; wa.bo = bo;
    hipLaunchKernelGGL(wfuse_kernel, dim3(879), dim3(256), 0, stream, wa);

    // ---- D3: xz_{f,b} = xn @ Wz + bz (K=768, ip folded in) ----
    hipLaunchKernelGGL((mfma_gemm_k<128, 128, true>), dim3(12, 32, 2), dim3(256), 0, stream,
                       xn_bf, xn_bf, 768, WzF, WzB, 768, bzf, bzb,
                       (void*)xz_f_bf, (void*)xz_b_bf, 1536, 1536, 768);

    // ---- D4: conv + silu ----
    hipLaunchKernelGGL(conv_silu_kernel, dim3(ROWS * DINNER / 256, 2), dim3(256), 0, stream,
                       xz_f_bf, xz_b_bf, f_conv_w, f_conv_b, b_conv_w, b_conv_b,
                       xc_f_bf, xc_b_bf);

    // ---- D5: xd64 = xc @ xp_w (bf16 out; TM=32 -> 256 blocks, R11) ----
    hipLaunchKernelGGL((mfma_gemm_k<32, 64, true>), dim3(1, 128, 2), dim3(256), 0, stream,
                       xc_f_bf, xc_b_bf, 768, Wt_fxp, Wt_bxp, 768,
                       (const float*)nullptr, (const float*)nullptr,
                       (void*)xd64_f, (void*)xd64_b, 64, 64, 768);

    // ---- D6: dt = softplus(xd64 @ dtwT + dt_b), K=64, bf16 out ----
    hipLaunchKernelGGL(dt_kernel, dim3(12, 32, 2), dim3(256), 0, stream,
                       xd64_f, xd64_b, dtwT_f, dtwT_b, f_dt_b, b_dt_b, dt_f, dt_b);

    // ---- D7/D8/D9: chunked selective scan ----
    hipLaunchKernelGGL((scan_chunk_kernel<false>), dim3(DINNER / 256, NCH, 4), dim3(256), 0, stream,
                       dt_f, xc_f_bf, xd64_f, xz_f_bf, f_A_log, f_D,
                       dt_b, xc_b_bf, xd64_b, xz_b_bf, b_A_log, b_D,
                       Hloc, Wpb, (const float*)nullptr, (ushort*)nullptr, (ushort*)nullptr);
    hipLaunchKernelGGL(scan_combine, dim3(4 * DINNER * 16 / 256), dim3(256), 0, stream,
                       Hloc, Wpb, Hin);
    hipLaunchKernelGGL((scan_chunk_kernel<true>), dim3(DINNER / 256, NCH, 4), dim3(256), 0, stream,
                       dt_f, xc_f_bf, xd64_f, xz_f_bf, f_A_log, f_D,
                       dt_b, xc_b_bf, xd64_b, xz_b_bf, b_A_log, b_D,
                       (float*)nullptr, (float*)nullptr, Hin, y_f_bf, y_b_bf);

    // ---- D10: outraw = y_f @ WoF + y_b @ WoB + bo (64x64 tiles, R11) ----
    hipLaunchKernelGGL((outop_kernel<64, 64>), dim3(12, 64), dim3(256), 0, stream,
                       y_f_bf, WoF, y_b_bf, WoB, bo, outraw, 768, 768, 768, 768, 768);

    // ---- D11: final layernorm(residual + out) ----
    hipLaunchKernelGGL(ln2_kernel, dim3(ROWS), dim3(256), 0, stream,
                       x, outraw, norm_w, norm_b, (float*)d_out);
}